// Round 5
// baseline (128.900 us; speedup 1.0000x reference)
//
#include <hip/hip_runtime.h>
#include <math.h>

// Problem constants (B=2, C=128, N=256, H=64, CH=256)
#define BB 2
#define CC 128
#define NN 256
#define HH 64
#define CHX 256
#define COLS 768           // 3*N flattened (v,n) columns
#define NEG_ATTN 0.2f
#define NEG_FFN 0.1f

typedef __attribute__((ext_vector_type(8))) short short8b;   // 8 bf16 (4 VGPRs)
typedef __attribute__((ext_vector_type(4))) float f32x4;

__device__ __forceinline__ unsigned bf16rne(float x) {
  unsigned u = __float_as_uint(x);
  return (u + 0x7fffu + ((u >> 16) & 1u)) >> 16;
}

// ---------------------------------------------------------------------------
// K1: q,k,v = Wq/Wk/Wv @ x.  grid (24 coltiles-32, which*2+cohalf, B), 256 thr.
// Block: 64co x 32col, K=128 in 4 chunks of 32 (W chunk staged in LDS).
// Thread: 2co x 4col.
// ---------------------------------------------------------------------------
__global__ __launch_bounds__(256) void k_qkv(
    const float* __restrict__ x, const float* __restrict__ Wq,
    const float* __restrict__ Wk, const float* __restrict__ Wv,
    float* __restrict__ q_t, float* __restrict__ k_nat, float* __restrict__ v_t)
{
  const int ct = blockIdx.x, b = blockIdx.z;
  const int which = blockIdx.y >> 1, cohalf = blockIdx.y & 1;
  const int col0 = ct * 32, co0 = cohalf * 64;
  const int t = threadIdx.x;
  __shared__ __align__(16) float xt[CC][32];   // 16 KB
  __shared__ float Wl[64][33];                 // 8.4 KB
  const float* xb = x + (size_t)b * CC * COLS;
  for (int idx = t; idx < CC * 32; idx += 256) {
    int r = idx >> 5, cc = idx & 31;
    xt[r][cc] = xb[r * COLS + col0 + cc];
  }
  const float* W = (which == 0) ? Wq : ((which == 1) ? Wk : Wv);
  const int cop = t >> 3;            // co pair index (0..31)
  const int colq = t & 7;            // col quad (0..7)
  float acc[2][4];
#pragma unroll
  for (int r = 0; r < 2; r++)
#pragma unroll
    for (int k = 0; k < 4; k++) acc[r][k] = 0.f;
  for (int cu = 0; cu < 4; cu++) {
    __syncthreads();
    for (int idx = t; idx < 64 * 32; idx += 256) {
      int row = idx >> 5, ci = idx & 31;
      Wl[row][ci] = W[(size_t)(co0 + row) * CC + cu * 32 + ci];
    }
    __syncthreads();
#pragma unroll 8
    for (int ci = 0; ci < 32; ci++) {
      float w0 = Wl[cop * 2][ci], w1 = Wl[cop * 2 + 1][ci];
      const float4 xv = *(reinterpret_cast<const float4*>(xt[cu * 32 + ci]) + colq);
      acc[0][0] = fmaf(w0, xv.x, acc[0][0]); acc[0][1] = fmaf(w0, xv.y, acc[0][1]);
      acc[0][2] = fmaf(w0, xv.z, acc[0][2]); acc[0][3] = fmaf(w0, xv.w, acc[0][3]);
      acc[1][0] = fmaf(w1, xv.x, acc[1][0]); acc[1][1] = fmaf(w1, xv.y, acc[1][1]);
      acc[1][2] = fmaf(w1, xv.z, acc[1][2]); acc[1][3] = fmaf(w1, xv.w, acc[1][3]);
    }
  }
#pragma unroll
  for (int r = 0; r < 2; r++) {
    const int co_g = co0 + cop * 2 + r;
    if (which == 1) {
      float4 o = {acc[r][0], acc[r][1], acc[r][2], acc[r][3]};
      *reinterpret_cast<float4*>(&k_nat[(size_t)(b * CC + co_g) * COLS + col0 + colq * 4]) = o;
    } else {
#pragma unroll
      for (int k = 0; k < 4; k++) {
        int col = col0 + colq * 4 + k;
        int v = col >> 8, n = col & 255;
        if (which == 0) q_t[((size_t)(b * NN + n) * CC + co_g) * 3 + v] = acc[r][k];
        else            v_t[((size_t)(b * NN + n) * 3 + v) * CC + co_g] = acc[r][k];
      }
    }
  }
}

// ---------------------------------------------------------------------------
// K1b: rel norms: rm_all[b][i][j], rp_all[b][i][j].
// grid (N/2, B), 256 threads (thread = j, 2 i's per block for k-reuse).
// ---------------------------------------------------------------------------
__global__ __launch_bounds__(256) void k_rel(
    const float* __restrict__ q_t, const float* __restrict__ k_nat,
    const float* __restrict__ pos, float* __restrict__ rm_all,
    float* __restrict__ rp_all)
{
  const int i0 = blockIdx.x * 2, b = blockIdx.y;
  const int t = threadIdx.x;
  __shared__ float qv[2 * CC * 3];
  for (int idx = t; idx < 2 * CC * 3; idx += 256)
    qv[idx] = q_t[(size_t)(b * NN + i0) * CC * 3 + idx];
  __syncthreads();
  const int j = t;
  const float* kb = k_nat + (size_t)b * CC * COLS;
  float a00 = 0.f, a01 = 0.f, a10 = 0.f, a11 = 0.f;
  for (int c = 0; c < CC; c += 2) {
    float kx0 = kb[c * COLS + j], ky0 = kb[c * COLS + 256 + j], kz0 = kb[c * COLS + 512 + j];
    float kx1 = kb[(c + 1) * COLS + j], ky1 = kb[(c + 1) * COLS + 256 + j], kz1 = kb[(c + 1) * COLS + 512 + j];
    {
      float dx = kx0 - qv[c * 3], dy = ky0 - qv[c * 3 + 1], dz = kz0 - qv[c * 3 + 2];
      float sq = dx * dx + dy * dy + dz * dz;
      a00 += (sq > 0.f) ? sqrtf(sq) : 0.f;
      dx = kx1 - qv[(c + 1) * 3]; dy = ky1 - qv[(c + 1) * 3 + 1]; dz = kz1 - qv[(c + 1) * 3 + 2];
      sq = dx * dx + dy * dy + dz * dz;
      a01 += (sq > 0.f) ? sqrtf(sq) : 0.f;
    }
    {
      const float* q1 = qv + CC * 3;
      float dx = kx0 - q1[c * 3], dy = ky0 - q1[c * 3 + 1], dz = kz0 - q1[c * 3 + 2];
      float sq = dx * dx + dy * dy + dz * dz;
      a10 += (sq > 0.f) ? sqrtf(sq) : 0.f;
      dx = kx1 - q1[(c + 1) * 3]; dy = ky1 - q1[(c + 1) * 3 + 1]; dz = kz1 - q1[(c + 1) * 3 + 2];
      sq = dx * dx + dy * dy + dz * dz;
      a11 += (sq > 0.f) ? sqrtf(sq) : 0.f;
    }
  }
  rm_all[(size_t)(b * NN + i0) * NN + j]     = (a00 + a01) * (1.f / 128.f);
  rm_all[(size_t)(b * NN + i0 + 1) * NN + j] = (a10 + a11) * (1.f / 128.f);
  float pjx = pos[(b * NN + j) * 3], pjy = pos[(b * NN + j) * 3 + 1], pjz = pos[(b * NN + j) * 3 + 2];
#pragma unroll
  for (int ii = 0; ii < 2; ii++) {
    float dx = pos[(b * NN + i0 + ii) * 3] - pjx;
    float dy = pos[(b * NN + i0 + ii) * 3 + 1] - pjy;
    float dz = pos[(b * NN + i0 + ii) * 3 + 2] - pjz;
    float sq = dx * dx + dy * dy + dz * dz;
    rp_all[(size_t)(b * NN + i0 + ii) * NN + j] = (sq > 0.f) ? sqrtf(sq) : 0.f;
  }
}

// ---------------------------------------------------------------------------
// K2: fused attention per (b, i, c-half). grid (N, 2, B), 256 threads.
// Score MLP via bf16 MFMA; exp applied DIRECTLY to the MFMA accumulator
// (D-layout: row j = jt*16+(lane>>4)*4+r, col c = wv*16+(lane&15)); (l, a)
// accumulate in registers per thread; one end-of-kernel 4-way j-group merge.
// hh double-buffered -> ONE barrier per q-tile. No running max (scores
// bounded: overflow needs s > 88 ~ 35 sigma).
// ---------------------------------------------------------------------------
__global__ __launch_bounds__(256, 4) void k_attn(
    const float* __restrict__ rm_all, const float* __restrict__ rp_all,
    const float* __restrict__ v_t, const float* __restrict__ W1,
    const float* __restrict__ b1, const float* __restrict__ W2,
    float* __restrict__ a_nat)
{
  const int i = blockIdx.x, chalf = blockIdx.y, b = blockIdx.z;
  const int t = threadIdx.x;
  __shared__ __align__(16) short hh_s[2][64 * 64];  // bf16, XOR-swizzled, dbuf (16 KB)
  __shared__ __align__(16) short w2_s[64 * 64];     // bf16, XOR-swizzled (8 KB)
  __shared__ float rm_s[NN], rp_s[NN];              // 2 KB
  __shared__ float mrg[64][3][4];                   // 3 KB

  rm_s[t] = rm_all[(size_t)(b * NN + i) * NN + t];
  rp_s[t] = rp_all[(size_t)(b * NN + i) * NN + t];
  {
    const int cl = t >> 2, h0 = (t & 3) * 16;
    const float* wrow = W2 + (size_t)(chalf * 64 + cl) * HH + h0;
#pragma unroll
    for (int e = 0; e < 8; e++) {
      unsigned lo = bf16rne(wrow[2 * e]);
      unsigned hi = bf16rne(wrow[2 * e + 1]);
      int didx = (cl * 32 + (h0 >> 1) + e) ^ ((cl & 7) << 2);
      ((unsigned*)w2_s)[didx] = lo | (hi << 16);
    }
  }
  const int h2 = (t & 31) * 2, jgrp = t >> 5;
  const float4 w1v = *reinterpret_cast<const float4*>(W1 + 2 * h2);
  const float c0 = b1[h2], c1 = b1[h2 + 1];

  auto phase2 = [&](int q) {
    unsigned* dst = (unsigned*)hh_s[q & 1];
#pragma unroll
    for (int jj = 0; jj < 8; jj++) {
      int jl = jgrp * 8 + jj;
      int jg = q * 64 + jl;
      float rmv = rm_s[jg], rpv = rp_s[jg];
      float g0 = fmaf(w1v.x, rmv, fmaf(w1v.y, rpv, c0));
      float g1 = fmaf(w1v.z, rmv, fmaf(w1v.w, rpv, c1));
      g0 = (g0 >= 0.f) ? g0 : NEG_ATTN * g0;
      g1 = (g1 >= 0.f) ? g1 : NEG_ATTN * g1;
      int didx = (jl * 32 + (h2 >> 1)) ^ ((jl & 7) << 2);
      dst[didx] = bf16rne(g0) | (bf16rne(g1) << 16);
    }
  };

  __syncthreads();   // rm_s/rp_s ready before phase2 reads them
  phase2(0);
  __syncthreads();

  const int lane = t & 63, wv = t >> 6;
  const int g8 = (lane >> 4) * 8;
  const int cdx = wv * 16 + (lane & 15);
  const short8b bfr0 = *reinterpret_cast<const short8b*>(&w2_s[(cdx * 64 + g8) ^ ((cdx & 7) << 3)]);
  const short8b bfr1 = *reinterpret_cast<const short8b*>(&w2_s[(cdx * 64 + 32 + g8) ^ ((cdx & 7) << 3)]);

  const int vc = chalf * 64 + cdx;   // this thread's output channel
  const int jg4 = (lane >> 4) * 4;   // j sub-offset from D-layout row
  float l = 0.f, a0 = 0.f, a1 = 0.f, a2 = 0.f;

  for (int q = 0; q < 4; q++) {
    const short* hb = hh_s[q & 1];
#pragma unroll
    for (int jt = 0; jt < 4; jt++) {
      int jr = jt * 16 + (lane & 15);
      short8b af0 = *reinterpret_cast<const short8b*>(&hb[(jr * 64 + g8) ^ ((jr & 7) << 3)]);
      short8b af1 = *reinterpret_cast<const short8b*>(&hb[(jr * 64 + 32 + g8) ^ ((jr & 7) << 3)]);
      f32x4 acc = {0.f, 0.f, 0.f, 0.f};
      acc = __builtin_amdgcn_mfma_f32_16x16x32_bf16(af0, bfr0, acc, 0, 0, 0);
      acc = __builtin_amdgcn_mfma_f32_16x16x32_bf16(af1, bfr1, acc, 0, 0, 0);
      const int jbase = q * 64 + jt * 16 + jg4;
#pragma unroll
      for (int r = 0; r < 4; r++) {
        float p = __expf(acc[r]);
        const float* vb = v_t + ((size_t)(b * NN + jbase + r) * 3) * CC + vc;
        l += p;
        a0 = fmaf(p, vb[0], a0);
        a1 = fmaf(p, vb[CC], a1);
        a2 = fmaf(p, vb[2 * CC], a2);
      }
    }
    if (q < 3) phase2(q + 1);
    __syncthreads();
  }

  // ---- merge the 4 j-groups per channel ----
  const int g = lane >> 4;
  const int cslot = cdx;             // 0..63 within block
  if (g != 0) {
    float* mp = &mrg[cslot][g - 1][0];
    mp[0] = l; mp[1] = a0; mp[2] = a1; mp[3] = a2;
  }
  __syncthreads();
  if (g == 0) {
    float L = l, A0 = a0, A1 = a1, A2 = a2;
#pragma unroll
    for (int gg = 0; gg < 3; gg++) {
      const float* mp = &mrg[cslot][gg][0];
      L += mp[0]; A0 += mp[1]; A1 += mp[2]; A2 += mp[3];
    }
    float inv = 1.f / L;
    float* ap = a_nat + (size_t)(b * CC + vc) * COLS + i;
    ap[0] = A0 * inv; ap[256] = A1 * inv; ap[512] = A2 * inv;
  }
}

// ---------------------------------------------------------------------------
// K3: y1 = x + Wo @ a_nat. grid (48 coltiles-16, 2 cohalf, B), 256 thr.
// ---------------------------------------------------------------------------
__global__ __launch_bounds__(256) void k_wo_res(
    const float* __restrict__ a_nat, const float* __restrict__ Wo,
    const float* __restrict__ x, float* __restrict__ y1)
{
  const int ct = blockIdx.x, cohalf = blockIdx.y, b = blockIdx.z;
  const int col0 = ct * 16, co0 = cohalf * 64;
  const int t = threadIdx.x;
  __shared__ __align__(16) float at[CC][16];
  __shared__ float Wl[64][33];
  const float* ab = a_nat + (size_t)b * CC * COLS;
  for (int idx = t; idx < CC * 16; idx += 256) {
    int r = idx >> 4, cc = idx & 15;
    at[r][cc] = ab[r * COLS + col0 + cc];
  }
  const int cop = t >> 3, colp = t & 7;
  float acc[2][2] = {{0.f, 0.f}, {0.f, 0.f}};
  for (int cu = 0; cu < 4; cu++) {
    __syncthreads();
    for (int idx = t; idx < 64 * 32; idx += 256) {
      int row = idx >> 5, ci = idx & 31;
      Wl[row][ci] = Wo[(size_t)(co0 + row) * CC + cu * 32 + ci];
    }
    __syncthreads();
#pragma unroll 8
    for (int ci = 0; ci < 32; ci++) {
      float w0 = Wl[cop * 2][ci], w1 = Wl[cop * 2 + 1][ci];
      const float2 xv = *(reinterpret_cast<const float2*>(at[cu * 32 + ci]) + colp);
      acc[0][0] = fmaf(w0, xv.x, acc[0][0]); acc[0][1] = fmaf(w0, xv.y, acc[0][1]);
      acc[1][0] = fmaf(w1, xv.x, acc[1][0]); acc[1][1] = fmaf(w1, xv.y, acc[1][1]);
    }
  }
#pragma unroll
  for (int r = 0; r < 2; r++) {
    const size_t base = (size_t)(b * CC + co0 + cop * 2 + r) * COLS + col0 + colp * 2;
    y1[base]     = x[base]     + acc[r][0];
    y1[base + 1] = x[base + 1] + acc[r][1];
  }
}

// ---------------------------------------------------------------------------
// K4: partial ZCA stats. grid (32, B), 256 thr; 4 elements/thread.
// ---------------------------------------------------------------------------
__global__ __launch_bounds__(256) void k_stats1(
    const float* __restrict__ y, float* __restrict__ partials)
{
  const int blk = blockIdx.x, b = blockIdx.y;
  const float* yb = y + (size_t)b * CC * COLS;
  float v9[9];
#pragma unroll
  for (int k = 0; k < 9; k++) v9[k] = 0.f;
#pragma unroll
  for (int e = 0; e < 4; e++) {
    int idx = blk * 1024 + e * 256 + threadIdx.x;
    int cidx = idx >> 8, n = idx & 255;
    const float* row = yb + cidx * COLS + n;
    float v0 = row[0], v1 = row[256], v2 = row[512];
    v9[0] += v0; v9[1] += v1; v9[2] += v2;
    v9[3] += v0 * v0; v9[4] += v0 * v1; v9[5] += v0 * v2;
    v9[6] += v1 * v1; v9[7] += v1 * v2; v9[8] += v2 * v2;
  }
#pragma unroll
  for (int off = 32; off >= 1; off >>= 1)
#pragma unroll
    for (int k = 0; k < 9; k++) v9[k] += __shfl_down(v9[k], off);
  __shared__ float red[4][9];
  const int wid = threadIdx.x >> 6, lane = threadIdx.x & 63;
  if (lane == 0)
#pragma unroll
    for (int k = 0; k < 9; k++) red[wid][k] = v9[k];
  __syncthreads();
  if (threadIdx.x == 0) {
#pragma unroll
    for (int k = 0; k < 9; k++)
      partials[(size_t)(b * 32 + blk) * 9 + k] =
          ((red[0][k] + red[1][k]) + (red[2][k] + red[3][k]));
  }
}

// ---------------------------------------------------------------------------
// K5: finalize ZCA: reduce partials, 3x3 Jacobi eigh, whitening matrix.
// ---------------------------------------------------------------------------
__global__ __launch_bounds__(64) void k_zca_fin(
    const float* __restrict__ partials, float* __restrict__ stats)
{
  const int b = blockIdx.x;
  if (threadIdx.x != 0) return;
  float tot[9];
#pragma unroll
  for (int k = 0; k < 9; k++) tot[k] = 0.f;
  for (int p = 0; p < 32; p++)
#pragma unroll
    for (int k = 0; k < 9; k++) tot[k] += partials[(size_t)(b * 32 + p) * 9 + k];
  const float M = (float)(CC * NN);
  float mu0 = tot[0] / M, mu1 = tot[1] / M, mu2 = tot[2] / M;
  float A[3][3];
  A[0][0] = (tot[3] - M * mu0 * mu0) / M + 1e-5f;
  A[0][1] = A[1][0] = (tot[4] - M * mu0 * mu1) / M;
  A[0][2] = A[2][0] = (tot[5] - M * mu0 * mu2) / M;
  A[1][1] = (tot[6] - M * mu1 * mu1) / M + 1e-5f;
  A[1][2] = A[2][1] = (tot[7] - M * mu1 * mu2) / M;
  A[2][2] = (tot[8] - M * mu2 * mu2) / M + 1e-5f;
  float V[3][3] = {{1.f, 0.f, 0.f}, {0.f, 1.f, 0.f}, {0.f, 0.f, 1.f}};
  for (int sweep = 0; sweep < 10; sweep++) {
    for (int pi = 0; pi < 3; pi++) {
      const int p = (pi == 2) ? 1 : 0;
      const int q = (pi == 0) ? 1 : 2;
      float apq = A[p][q];
      if (fabsf(apq) < 1e-30f) continue;
      float theta = (A[q][q] - A[p][p]) / (2.f * apq);
      float tt = 1.f / (fabsf(theta) + sqrtf(theta * theta + 1.f));
      if (theta < 0.f) tt = -tt;
      float cr = 1.f / sqrtf(tt * tt + 1.f);
      float sr = tt * cr;
      float app = A[p][p], aqq = A[q][q];
      A[p][p] = app - tt * apq;
      A[q][q] = aqq + tt * apq;
      A[p][q] = A[q][p] = 0.f;
      const int r = 3 - p - q;
      float arp = A[r][p], arq = A[r][q];
      A[r][p] = A[p][r] = cr * arp - sr * arq;
      A[r][q] = A[q][r] = sr * arp + cr * arq;
      for (int rr = 0; rr < 3; rr++) {
        float vrp = V[rr][p], vrq = V[rr][q];
        V[rr][p] = cr * vrp - sr * vrq;
        V[rr][q] = sr * vrp + cr * vrq;
      }
    }
  }
  float rs[3];
#pragma unroll
  for (int k = 0; k < 3; k++) rs[k] = rsqrtf(fmaxf(A[k][k], 1e-5f));
  float* st = stats + b * 12;
  st[0] = mu0; st[1] = mu1; st[2] = mu2;
  for (int u = 0; u < 3; u++)
    for (int v = 0; v < 3; v++) {
      float acc = 0.f;
      for (int k = 0; k < 3; k++) acc += V[u][k] * rs[k] * V[v][k];
      st[3 + u * 3 + v] = acc;
    }
}

// ---------------------------------------------------------------------------
// K6: FFN1, whitening fused on read, W chunks in LDS.
// grid (32 ntiles-8, 8 co-tiles-32, B) = 512 blocks. Thread: (co, n).
// ---------------------------------------------------------------------------
__global__ __launch_bounds__(256) void k_ffn1(
    const float* __restrict__ y1, const float* __restrict__ stats,
    const float* __restrict__ gamma, const float* __restrict__ Wfeat,
    const float* __restrict__ Wdir, float* __restrict__ hout)
{
  const int nt = blockIdx.x, cs = blockIdx.y, b = blockIdx.z;
  const int n0 = nt * 8, co0 = cs * 32;
  const int t = threadIdx.x;
  __shared__ float xt[CC][24];     // [ci][v*8+nn] whitened, 12 KB
  __shared__ float Wfl[32][33], Wdl[32][33];
  const float* yb = y1 + (size_t)b * CC * COLS;
  const float* st = stats + b * 12;
  for (int idx = t; idx < CC * 8; idx += 256) {
    int ci = idx >> 3, nn = idx & 7;
    const float* row = yb + ci * COLS + n0 + nn;
    float d0 = row[0] - st[0], d1 = row[256] - st[1], d2 = row[512] - st[2];
    float g = gamma[ci];
    xt[ci][nn]      = g * (st[3] * d0 + st[4] * d1 + st[5] * d2);
    xt[ci][8 + nn]  = g * (st[6] * d0 + st[7] * d1 + st[8] * d2);
    xt[ci][16 + nn] = g * (st[9] * d0 + st[10] * d1 + st[11] * d2);
  }
  const int co = t >> 3, nn = t & 7;
  float p[3] = {0.f, 0.f, 0.f}, d[3] = {0.f, 0.f, 0.f};
  for (int cu = 0; cu < 4; cu++) {
    __syncthreads();
    for (int idx = t; idx < 2048; idx += 256) {
      int row = (idx & 1023) >> 5, ci = idx & 31;
      if (idx < 1024) Wfl[row][ci] = Wfeat[(size_t)(co0 + row) * CC + cu * 32 + ci];
      else            Wdl[row][ci] = Wdir[(size_t)(co0 + row) * CC + cu * 32 + ci];
    }
    __syncthreads();
#pragma unroll 8
    for (int ci = 0; ci < 32; ci++) {
      float wf = Wfl[co][ci], wd = Wdl[co][ci];
      const float* xr = xt[cu * 32 + ci];
      float x0 = xr[nn], x1 = xr[8 + nn], x2 = xr[16 + nn];
      p[0] = fmaf(wf, x0, p[0]); p[1] = fmaf(wf, x1, p[1]); p[2] = fmaf(wf, x2, p[2]);
      d[0] = fmaf(wd, x0, d[0]); d[1] = fmaf(wd, x1, d[1]); d[2] = fmaf(wd, x2, d[2]);
    }
  }
  float dot = p[0] * d[0] + p[1] * d[1] + p[2] * d[2];
  float dsq = d[0] * d[0] + d[1] * d[1] + d[2] * d[2];
  float coef = (dot >= 0.f) ? 0.f : (1.f - NEG_FFN) * dot / (dsq + 1e-6f);
  float* hb = hout + (size_t)(b * CHX + co0 + co) * COLS;
#pragma unroll
  for (int v = 0; v < 3; v++)
    hb[v * 256 + n0 + nn] = p[v] - coef * d[v];
}

// ---------------------------------------------------------------------------
// K7: x2 = whiten(y1) + Wffn2 @ h. grid (48 coltiles-16, 2 cohalf, B).
// ---------------------------------------------------------------------------
__global__ __launch_bounds__(256) void k_ffn2(
    const float* __restrict__ h, const float* __restrict__ Wffn2,
    const float* __restrict__ y1, const float* __restrict__ stats,
    const float* __restrict__ gamma, float* __restrict__ x2)
{
  const int ct = blockIdx.x, cohalf = blockIdx.y, b = blockIdx.z;
  const int col0 = ct * 16, co0 = cohalf * 64;
  const int t = threadIdx.x;
  __shared__ __align__(16) float ht[CHX][16];  // 16 KB
  __shared__ float Wl[64][33];
  const float* hb = h + (size_t)b * CHX * COLS;
  for (int idx = t; idx < CHX * 16; idx += 256) {
    int r = idx >> 4, cc = idx & 15;
    ht[r][cc] = hb[r * COLS + col0 + cc];
  }
  const int cop = t >> 3, colp = t & 7;
  float acc[2][2] = {{0.f, 0.f}, {0.f, 0.f}};
  for (int cu = 0; cu < 8; cu++) {
    __syncthreads();
    for (int idx = t; idx < 64 * 32; idx += 256) {
      int row = idx >> 5, ci = idx & 31;
      Wl[row][ci] = Wffn2[(size_t)(co0 + row) * CHX + cu * 32 + ci];
    }
    __syncthreads();
#pragma unroll 8
    for (int ci = 0; ci < 32; ci++) {
      float w0 = Wl[cop * 2][ci], w1 = Wl[cop * 2 + 1][ci];
      const float2 xv = *(reinterpret_cast<const float2*>(ht[cu * 32 + ci]) + colp);
      acc[0][0] = fmaf(w0, xv.x, acc[0][0]); acc[0][1] = fmaf(w0, xv.y, acc[0][1]);
      acc[1][0] = fmaf(w1, xv.x, acc[1][0]); acc[1][1] = fmaf(w1, xv.y, acc[1][1]);
    }
  }
  const int col_base = col0 + colp * 2;
  const int v = col_base >> 8, n = col_base & 255;
  const float* st = stats + b * 12;
  const float w0 = st[3 + v * 3 + 0], w1 = st[3 + v * 3 + 1], w2 = st[3 + v * 3 + 2];
#pragma unroll
  for (int r = 0; r < 2; r++) {
    const int co_g = co0 + cop * 2 + r;
    const float g = gamma[co_g];
    const float* yr = y1 + (size_t)(b * CC + co_g) * COLS + n;
    const size_t base = (size_t)(b * CC + co_g) * COLS + col_base;
#pragma unroll
    for (int k = 0; k < 2; k++) {
      float d0 = yr[k] - st[0], d1 = yr[256 + k] - st[1], d2 = yr[512 + k] - st[2];
      x2[base + k] = g * (w0 * d0 + w1 * d1 + w2 * d2) + acc[r][k];
    }
  }
}

// ---------------------------------------------------------------------------
// K8: final whitening apply -> out. grid (256), 256 thr.
// ---------------------------------------------------------------------------
__global__ __launch_bounds__(256) void k_zca_apply(
    const float* __restrict__ y, const float* __restrict__ stats,
    const float* __restrict__ gamma, float* __restrict__ out)
{
  int idx = blockIdx.x * blockDim.x + threadIdx.x;
  int b = idx >> 15, rem = idx & 32767;
  int cidx = rem >> 8, n = rem & 255;
  const float* st = stats + b * 12;
  const size_t base = (size_t)(b * CC + cidx) * COLS + n;
  float v0 = y[base] - st[0];
  float v1 = y[base + 256] - st[1];
  float v2 = y[base + 512] - st[2];
  float g = gamma[cidx];
  out[base]       = g * (st[3] * v0 + st[4] * v1 + st[5] * v2);
  out[base + 256] = g * (st[6] * v0 + st[7] * v1 + st[8] * v2);
  out[base + 512] = g * (st[9] * v0 + st[10] * v1 + st[11] * v2);
}

// ---------------------------------------------------------------------------
extern "C" void kernel_launch(void* const* d_in, const int* in_sizes, int n_in,
                              void* d_out, int out_size, void* d_ws, size_t ws_size,
                              hipStream_t stream)
{
  (void)in_sizes; (void)n_in; (void)out_size; (void)ws_size;
  const float* x      = (const float*)d_in[0];
  const float* pos    = (const float*)d_in[1];
  const float* Wq     = (const float*)d_in[2];
  const float* Wk     = (const float*)d_in[3];
  const float* Wv     = (const float*)d_in[4];
  const float* Wo     = (const float*)d_in[5];
  const float* W1     = (const float*)d_in[6];
  const float* b1     = (const float*)d_in[7];
  const float* W2     = (const float*)d_in[8];
  // d_in[9] = b2 : dropped (softmax shift-invariant per channel)
  const float* gamma1 = (const float*)d_in[10];
  const float* Wfeat  = (const float*)d_in[11];
  const float* Wdir   = (const float*)d_in[12];
  const float* Wffn2  = (const float*)d_in[13];
  const float* gamma2 = (const float*)d_in[14];

  float* ws = (float*)d_ws;
  const size_t SZ = (size_t)BB * CC * 3 * NN;   // 393216 floats
  const size_t RMSZ = (size_t)BB * NN * NN;     // 131072 floats
  float* q_t    = ws;                  // dead after k_rel
  float* k_nat  = ws + SZ;             // dead after k_rel
  float* v_t    = ws + 2 * SZ;         // dead after k_attn
  float* rm_all = ws + 3 * SZ;         // dead after k_attn
  float* rp_all = ws + 3 * SZ + RMSZ;  // dead after k_attn
  float* a_nat  = ws;                  // alias q_t
  float* y1     = ws + SZ;             // alias k_nat
  float* hbuf   = ws + 2 * SZ;         // [2SZ, 4SZ), alias v_t+rm+rp
  float* x2     = ws;                  // alias a_nat (dead after k_wo_res)
  float* part   = ws + 4 * SZ;         // 576 floats
  float* stats1 = ws + 4 * SZ + 640;   // 24 floats
  float* stats2 = ws + 4 * SZ + 704;   // 24 floats

  k_qkv<<<dim3(24, 6, BB), 256, 0, stream>>>(x, Wq, Wk, Wv, q_t, k_nat, v_t);
  k_rel<<<dim3(NN / 2, BB), 256, 0, stream>>>(q_t, k_nat, pos, rm_all, rp_all);
  k_attn<<<dim3(NN, 2, BB), 256, 0, stream>>>(rm_all, rp_all, v_t, W1, b1, W2, a_nat);
  k_wo_res<<<dim3(48, 2, BB), 256, 0, stream>>>(a_nat, Wo, x, y1);
  k_stats1<<<dim3(32, BB), 256, 0, stream>>>(y1, part);
  k_zca_fin<<<BB, 64, 0, stream>>>(part, stats1);
  k_ffn1<<<dim3(32, 8, BB), 256, 0, stream>>>(y1, stats1, gamma1, Wfeat, Wdir, hbuf);
  k_ffn2<<<dim3(48, 2, BB), 256, 0, stream>>>(hbuf, Wffn2, y1, stats1, gamma1, x2);
  k_stats1<<<dim3(32, BB), 256, 0, stream>>>(x2, part);
  k_zca_fin<<<BB, 64, 0, stream>>>(part, stats2);
  k_zca_apply<<<256, 256, 0, stream>>>(x2, stats2, gamma2, (float*)d_out);
}

// Round 6
// 124.951 us; speedup vs baseline: 1.0316x; 1.0316x over previous
//
#include <hip/hip_runtime.h>
#include <math.h>

// Problem constants (B=2, C=128, N=256, H=64, CH=256)
#define BB 2
#define CC 128
#define NN 256
#define HH 64
#define CHX 256
#define COLS 768           // 3*N flattened (v,n) columns
#define NEG_ATTN 0.2f
#define NEG_FFN 0.1f

typedef __attribute__((ext_vector_type(8))) short short8b;   // 8 bf16 (4 VGPRs)
typedef __attribute__((ext_vector_type(4))) float f32x4;

__device__ __forceinline__ unsigned bf16rne(float x) {
  unsigned u = __float_as_uint(x);
  return (u + 0x7fffu + ((u >> 16) & 1u)) >> 16;
}

// ---------------------------------------------------------------------------
// K1: q,k,v = Wq/Wk/Wv @ x.  grid (24 coltiles-32, which*2+cohalf, B), 256 thr.
// Block: 64co x 32col, K=128 in 4 chunks of 32 (W chunk staged in LDS).
// Thread: 2co x 4col.
// ---------------------------------------------------------------------------
__global__ __launch_bounds__(256) void k_qkv(
    const float* __restrict__ x, const float* __restrict__ Wq,
    const float* __restrict__ Wk, const float* __restrict__ Wv,
    float* __restrict__ q_t, float* __restrict__ k_nat, float* __restrict__ v_t)
{
  const int ct = blockIdx.x, b = blockIdx.z;
  const int which = blockIdx.y >> 1, cohalf = blockIdx.y & 1;
  const int col0 = ct * 32, co0 = cohalf * 64;
  const int t = threadIdx.x;
  __shared__ __align__(16) float xt[CC][32];   // 16 KB
  __shared__ float Wl[64][33];                 // 8.4 KB
  const float* xb = x + (size_t)b * CC * COLS;
  for (int idx = t; idx < CC * 32; idx += 256) {
    int r = idx >> 5, cc = idx & 31;
    xt[r][cc] = xb[r * COLS + col0 + cc];
  }
  const float* W = (which == 0) ? Wq : ((which == 1) ? Wk : Wv);
  const int cop = t >> 3;            // co pair index (0..31)
  const int colq = t & 7;            // col quad (0..7)
  float acc[2][4];
#pragma unroll
  for (int r = 0; r < 2; r++)
#pragma unroll
    for (int k = 0; k < 4; k++) acc[r][k] = 0.f;
  for (int cu = 0; cu < 4; cu++) {
    __syncthreads();
    for (int idx = t; idx < 64 * 32; idx += 256) {
      int row = idx >> 5, ci = idx & 31;
      Wl[row][ci] = W[(size_t)(co0 + row) * CC + cu * 32 + ci];
    }
    __syncthreads();
#pragma unroll 8
    for (int ci = 0; ci < 32; ci++) {
      float w0 = Wl[cop * 2][ci], w1 = Wl[cop * 2 + 1][ci];
      const float4 xv = *(reinterpret_cast<const float4*>(xt[cu * 32 + ci]) + colq);
      acc[0][0] = fmaf(w0, xv.x, acc[0][0]); acc[0][1] = fmaf(w0, xv.y, acc[0][1]);
      acc[0][2] = fmaf(w0, xv.z, acc[0][2]); acc[0][3] = fmaf(w0, xv.w, acc[0][3]);
      acc[1][0] = fmaf(w1, xv.x, acc[1][0]); acc[1][1] = fmaf(w1, xv.y, acc[1][1]);
      acc[1][2] = fmaf(w1, xv.z, acc[1][2]); acc[1][3] = fmaf(w1, xv.w, acc[1][3]);
    }
  }
#pragma unroll
  for (int r = 0; r < 2; r++) {
    const int co_g = co0 + cop * 2 + r;
    if (which == 1) {
      float4 o = {acc[r][0], acc[r][1], acc[r][2], acc[r][3]};
      *reinterpret_cast<float4*>(&k_nat[(size_t)(b * CC + co_g) * COLS + col0 + colq * 4]) = o;
    } else {
#pragma unroll
      for (int k = 0; k < 4; k++) {
        int col = col0 + colq * 4 + k;
        int v = col >> 8, n = col & 255;
        if (which == 0) q_t[((size_t)(b * NN + n) * CC + co_g) * 3 + v] = acc[r][k];
        else            v_t[((size_t)(b * NN + n) * 3 + v) * CC + co_g] = acc[r][k];
      }
    }
  }
}

// ---------------------------------------------------------------------------
// K1b: rel norms: rm_all[b][i][j], rp_all[b][i][j].
// grid (N/2, B), 256 threads (thread = j, 2 i's per block for k-reuse).
// ---------------------------------------------------------------------------
__global__ __launch_bounds__(256) void k_rel(
    const float* __restrict__ q_t, const float* __restrict__ k_nat,
    const float* __restrict__ pos, float* __restrict__ rm_all,
    float* __restrict__ rp_all)
{
  const int i0 = blockIdx.x * 2, b = blockIdx.y;
  const int t = threadIdx.x;
  __shared__ float qv[2 * CC * 3];
  for (int idx = t; idx < 2 * CC * 3; idx += 256)
    qv[idx] = q_t[(size_t)(b * NN + i0) * CC * 3 + idx];
  __syncthreads();
  const int j = t;
  const float* kb = k_nat + (size_t)b * CC * COLS;
  float a00 = 0.f, a01 = 0.f, a10 = 0.f, a11 = 0.f;
  for (int c = 0; c < CC; c += 2) {
    float kx0 = kb[c * COLS + j], ky0 = kb[c * COLS + 256 + j], kz0 = kb[c * COLS + 512 + j];
    float kx1 = kb[(c + 1) * COLS + j], ky1 = kb[(c + 1) * COLS + 256 + j], kz1 = kb[(c + 1) * COLS + 512 + j];
    {
      float dx = kx0 - qv[c * 3], dy = ky0 - qv[c * 3 + 1], dz = kz0 - qv[c * 3 + 2];
      float sq = dx * dx + dy * dy + dz * dz;
      a00 += (sq > 0.f) ? sqrtf(sq) : 0.f;
      dx = kx1 - qv[(c + 1) * 3]; dy = ky1 - qv[(c + 1) * 3 + 1]; dz = kz1 - qv[(c + 1) * 3 + 2];
      sq = dx * dx + dy * dy + dz * dz;
      a01 += (sq > 0.f) ? sqrtf(sq) : 0.f;
    }
    {
      const float* q1 = qv + CC * 3;
      float dx = kx0 - q1[c * 3], dy = ky0 - q1[c * 3 + 1], dz = kz0 - q1[c * 3 + 2];
      float sq = dx * dx + dy * dy + dz * dz;
      a10 += (sq > 0.f) ? sqrtf(sq) : 0.f;
      dx = kx1 - q1[(c + 1) * 3]; dy = ky1 - q1[(c + 1) * 3 + 1]; dz = kz1 - q1[(c + 1) * 3 + 2];
      sq = dx * dx + dy * dy + dz * dz;
      a11 += (sq > 0.f) ? sqrtf(sq) : 0.f;
    }
  }
  rm_all[(size_t)(b * NN + i0) * NN + j]     = (a00 + a01) * (1.f / 128.f);
  rm_all[(size_t)(b * NN + i0 + 1) * NN + j] = (a10 + a11) * (1.f / 128.f);
  float pjx = pos[(b * NN + j) * 3], pjy = pos[(b * NN + j) * 3 + 1], pjz = pos[(b * NN + j) * 3 + 2];
#pragma unroll
  for (int ii = 0; ii < 2; ii++) {
    float dx = pos[(b * NN + i0 + ii) * 3] - pjx;
    float dy = pos[(b * NN + i0 + ii) * 3 + 1] - pjy;
    float dz = pos[(b * NN + i0 + ii) * 3 + 2] - pjz;
    float sq = dx * dx + dy * dy + dz * dz;
    rp_all[(size_t)(b * NN + i0 + ii) * NN + j] = (sq > 0.f) ? sqrtf(sq) : 0.f;
  }
}

// ---------------------------------------------------------------------------
// K2: fused attention per (b, i, c-half). grid (N, 2, B), 256 threads.
// Round-3 structure: MFMA -> fp32 scores to padded LDS -> coalesced PV with
// c = lane (64-contiguous channel loads). No running max (scores bounded).
// ---------------------------------------------------------------------------
__global__ __launch_bounds__(256, 4) void k_attn(
    const float* __restrict__ rm_all, const float* __restrict__ rp_all,
    const float* __restrict__ v_t, const float* __restrict__ W1,
    const float* __restrict__ b1, const float* __restrict__ W2,
    float* __restrict__ a_nat)
{
  const int i = blockIdx.x, chalf = blockIdx.y, b = blockIdx.z;
  const int t = threadIdx.x;
  __shared__ __align__(16) short hh_s[64 * 64];   // bf16 bits, XOR-swizzled
  __shared__ __align__(16) short w2_s[64 * 64];   // bf16 bits, XOR-swizzled
  __shared__ float sc_s[64 * 65];                 // fp32 scores (padded)
  __shared__ float rm_s[NN], rp_s[NN];

  rm_s[t] = rm_all[(size_t)(b * NN + i) * NN + t];
  rp_s[t] = rp_all[(size_t)(b * NN + i) * NN + t];
  {
    const int cl = t >> 2, h0 = (t & 3) * 16;
    const float* wrow = W2 + (size_t)(chalf * 64 + cl) * HH + h0;
#pragma unroll
    for (int e = 0; e < 8; e++) {
      unsigned lo = bf16rne(wrow[2 * e]);
      unsigned hi = bf16rne(wrow[2 * e + 1]);
      int didx = (cl * 32 + (h0 >> 1) + e) ^ ((cl & 7) << 2);
      ((unsigned*)w2_s)[didx] = lo | (hi << 16);
    }
  }
  const int h2 = (t & 31) * 2, jgrp = t >> 5;
  const float4 w1v = *reinterpret_cast<const float4*>(W1 + 2 * h2);
  const float c0 = b1[h2], c1 = b1[h2 + 1];
  __syncthreads();

  auto phase2 = [&](int q) {
#pragma unroll
    for (int jj = 0; jj < 8; jj++) {
      int jl = jgrp * 8 + jj;
      int jg = q * 64 + jl;
      float rmv = rm_s[jg], rpv = rp_s[jg];
      float g0 = fmaf(w1v.x, rmv, fmaf(w1v.y, rpv, c0));
      float g1 = fmaf(w1v.z, rmv, fmaf(w1v.w, rpv, c1));
      g0 = (g0 >= 0.f) ? g0 : NEG_ATTN * g0;
      g1 = (g1 >= 0.f) ? g1 : NEG_ATTN * g1;
      int didx = (jl * 32 + (h2 >> 1)) ^ ((jl & 7) << 2);
      ((unsigned*)hh_s)[didx] = bf16rne(g0) | (bf16rne(g1) << 16);
    }
  };

  phase2(0);
  __syncthreads();

  const int lane = t & 63, wv = t >> 6;
  const int g8 = (lane >> 4) * 8;
  const int cdx = wv * 16 + (lane & 15);
  const short8b bfr0 = *reinterpret_cast<const short8b*>(&w2_s[(cdx * 64 + g8) ^ ((cdx & 7) << 3)]);
  const short8b bfr1 = *reinterpret_cast<const short8b*>(&w2_s[(cdx * 64 + 32 + g8) ^ ((cdx & 7) << 3)]);

  const int cl = lane;
  const int par = wv;
  const int vc = chalf * 64 + cl;
  float l = 0.f, a0 = 0.f, a1 = 0.f, a2 = 0.f;

  for (int q = 0; q < 4; q++) {
#pragma unroll
    for (int jt = 0; jt < 4; jt++) {
      int jr = jt * 16 + (lane & 15);
      short8b af0 = *reinterpret_cast<const short8b*>(&hh_s[(jr * 64 + g8) ^ ((jr & 7) << 3)]);
      short8b af1 = *reinterpret_cast<const short8b*>(&hh_s[(jr * 64 + 32 + g8) ^ ((jr & 7) << 3)]);
      f32x4 acc = {0.f, 0.f, 0.f, 0.f};
      acc = __builtin_amdgcn_mfma_f32_16x16x32_bf16(af0, bfr0, acc, 0, 0, 0);
      acc = __builtin_amdgcn_mfma_f32_16x16x32_bf16(af1, bfr1, acc, 0, 0, 0);
      int row0 = jt * 16 + (lane >> 4) * 4;
      int ccol = wv * 16 + (lane & 15);
#pragma unroll
      for (int r = 0; r < 4; r++) sc_s[(row0 + r) * 65 + ccol] = acc[r];
    }
    __syncthreads();
    // ---- PV: exp-sums, no max, coalesced 64-lane channel loads ----
#pragma unroll
    for (int jj = 0; jj < 16; jj++) {
      int jl = jj * 4 + par;
      int jg = q * 64 + jl;
      float s = sc_s[jl * 65 + cl];
      const float* vb = v_t + ((size_t)(b * NN + jg) * 3) * CC + vc;
      float v0 = vb[0], v1 = vb[CC], v2 = vb[2 * CC];
      float p = __expf(s);
      l += p;
      a0 = fmaf(p, v0, a0);
      a1 = fmaf(p, v1, a1);
      a2 = fmaf(p, v2, a2);
    }
    if (q < 3) phase2(q + 1);
    __syncthreads();
  }

  // ---- merge the 4 j-parities per channel (mrg aliases sc_s) ----
  float* mrg = sc_s;
  if (par != 0) {
    float* mp = mrg + (cl * 3 + (par - 1)) * 4;
    mp[0] = l; mp[1] = a0; mp[2] = a1; mp[3] = a2;
  }
  __syncthreads();
  if (par == 0) {
    float L = l, A0 = a0, A1 = a1, A2 = a2;
#pragma unroll
    for (int q = 0; q < 3; q++) {
      const float* mp = mrg + (cl * 3 + q) * 4;
      L += mp[0]; A0 += mp[1]; A1 += mp[2]; A2 += mp[3];
    }
    float inv = 1.f / L;
    float* ap = a_nat + (size_t)(b * CC + vc) * COLS + i;
    ap[0] = A0 * inv; ap[256] = A1 * inv; ap[512] = A2 * inv;
  }
}

// ---------------------------------------------------------------------------
// K3: y1 = x + Wo @ a_nat. grid (48 coltiles-16, 2 cohalf, B), 256 thr.
// ---------------------------------------------------------------------------
__global__ __launch_bounds__(256) void k_wo_res(
    const float* __restrict__ a_nat, const float* __restrict__ Wo,
    const float* __restrict__ x, float* __restrict__ y1)
{
  const int ct = blockIdx.x, cohalf = blockIdx.y, b = blockIdx.z;
  const int col0 = ct * 16, co0 = cohalf * 64;
  const int t = threadIdx.x;
  __shared__ __align__(16) float at[CC][16];
  __shared__ float Wl[64][33];
  const float* ab = a_nat + (size_t)b * CC * COLS;
  for (int idx = t; idx < CC * 16; idx += 256) {
    int r = idx >> 4, cc = idx & 15;
    at[r][cc] = ab[r * COLS + col0 + cc];
  }
  const int cop = t >> 3, colp = t & 7;
  float acc[2][2] = {{0.f, 0.f}, {0.f, 0.f}};
  for (int cu = 0; cu < 4; cu++) {
    __syncthreads();
    for (int idx = t; idx < 64 * 32; idx += 256) {
      int row = idx >> 5, ci = idx & 31;
      Wl[row][ci] = Wo[(size_t)(co0 + row) * CC + cu * 32 + ci];
    }
    __syncthreads();
#pragma unroll 8
    for (int ci = 0; ci < 32; ci++) {
      float w0 = Wl[cop * 2][ci], w1 = Wl[cop * 2 + 1][ci];
      const float2 xv = *(reinterpret_cast<const float2*>(at[cu * 32 + ci]) + colp);
      acc[0][0] = fmaf(w0, xv.x, acc[0][0]); acc[0][1] = fmaf(w0, xv.y, acc[0][1]);
      acc[1][0] = fmaf(w1, xv.x, acc[1][0]); acc[1][1] = fmaf(w1, xv.y, acc[1][1]);
    }
  }
#pragma unroll
  for (int r = 0; r < 2; r++) {
    const size_t base = (size_t)(b * CC + co0 + cop * 2 + r) * COLS + col0 + colp * 2;
    y1[base]     = x[base]     + acc[r][0];
    y1[base + 1] = x[base + 1] + acc[r][1];
  }
}

// ---------------------------------------------------------------------------
// K4: partial ZCA stats. grid (32, B), 256 thr; 4 elements/thread.
// ---------------------------------------------------------------------------
__global__ __launch_bounds__(256) void k_stats1(
    const float* __restrict__ y, float* __restrict__ partials)
{
  const int blk = blockIdx.x, b = blockIdx.y;
  const float* yb = y + (size_t)b * CC * COLS;
  float v9[9];
#pragma unroll
  for (int k = 0; k < 9; k++) v9[k] = 0.f;
#pragma unroll
  for (int e = 0; e < 4; e++) {
    int idx = blk * 1024 + e * 256 + threadIdx.x;
    int cidx = idx >> 8, n = idx & 255;
    const float* row = yb + cidx * COLS + n;
    float v0 = row[0], v1 = row[256], v2 = row[512];
    v9[0] += v0; v9[1] += v1; v9[2] += v2;
    v9[3] += v0 * v0; v9[4] += v0 * v1; v9[5] += v0 * v2;
    v9[6] += v1 * v1; v9[7] += v1 * v2; v9[8] += v2 * v2;
  }
#pragma unroll
  for (int off = 32; off >= 1; off >>= 1)
#pragma unroll
    for (int k = 0; k < 9; k++) v9[k] += __shfl_down(v9[k], off);
  __shared__ float red[4][9];
  const int wid = threadIdx.x >> 6, lane = threadIdx.x & 63;
  if (lane == 0)
#pragma unroll
    for (int k = 0; k < 9; k++) red[wid][k] = v9[k];
  __syncthreads();
  if (threadIdx.x == 0) {
#pragma unroll
    for (int k = 0; k < 9; k++)
      partials[(size_t)(b * 32 + blk) * 9 + k] =
          ((red[0][k] + red[1][k]) + (red[2][k] + red[3][k]));
  }
}

// ---------------------------------------------------------------------------
// K5: finalize ZCA: reduce partials, 3x3 Jacobi eigh, whitening matrix.
// ---------------------------------------------------------------------------
__global__ __launch_bounds__(64) void k_zca_fin(
    const float* __restrict__ partials, float* __restrict__ stats)
{
  const int b = blockIdx.x;
  if (threadIdx.x != 0) return;
  float tot[9];
#pragma unroll
  for (int k = 0; k < 9; k++) tot[k] = 0.f;
  for (int p = 0; p < 32; p++)
#pragma unroll
    for (int k = 0; k < 9; k++) tot[k] += partials[(size_t)(b * 32 + p) * 9 + k];
  const float M = (float)(CC * NN);
  float mu0 = tot[0] / M, mu1 = tot[1] / M, mu2 = tot[2] / M;
  float A[3][3];
  A[0][0] = (tot[3] - M * mu0 * mu0) / M + 1e-5f;
  A[0][1] = A[1][0] = (tot[4] - M * mu0 * mu1) / M;
  A[0][2] = A[2][0] = (tot[5] - M * mu0 * mu2) / M;
  A[1][1] = (tot[6] - M * mu1 * mu1) / M + 1e-5f;
  A[1][2] = A[2][1] = (tot[7] - M * mu1 * mu2) / M;
  A[2][2] = (tot[8] - M * mu2 * mu2) / M + 1e-5f;
  float V[3][3] = {{1.f, 0.f, 0.f}, {0.f, 1.f, 0.f}, {0.f, 0.f, 1.f}};
  for (int sweep = 0; sweep < 10; sweep++) {
    for (int pi = 0; pi < 3; pi++) {
      const int p = (pi == 2) ? 1 : 0;
      const int q = (pi == 0) ? 1 : 2;
      float apq = A[p][q];
      if (fabsf(apq) < 1e-30f) continue;
      float theta = (A[q][q] - A[p][p]) / (2.f * apq);
      float tt = 1.f / (fabsf(theta) + sqrtf(theta * theta + 1.f));
      if (theta < 0.f) tt = -tt;
      float cr = 1.f / sqrtf(tt * tt + 1.f);
      float sr = tt * cr;
      float app = A[p][p], aqq = A[q][q];
      A[p][p] = app - tt * apq;
      A[q][q] = aqq + tt * apq;
      A[p][q] = A[q][p] = 0.f;
      const int r = 3 - p - q;
      float arp = A[r][p], arq = A[r][q];
      A[r][p] = A[p][r] = cr * arp - sr * arq;
      A[r][q] = A[q][r] = sr * arp + cr * arq;
      for (int rr = 0; rr < 3; rr++) {
        float vrp = V[rr][p], vrq = V[rr][q];
        V[rr][p] = cr * vrp - sr * vrq;
        V[rr][q] = sr * vrp + cr * vrq;
      }
    }
  }
  float rs[3];
#pragma unroll
  for (int k = 0; k < 3; k++) rs[k] = rsqrtf(fmaxf(A[k][k], 1e-5f));
  float* st = stats + b * 12;
  st[0] = mu0; st[1] = mu1; st[2] = mu2;
  for (int u = 0; u < 3; u++)
    for (int v = 0; v < 3; v++) {
      float acc = 0.f;
      for (int k = 0; k < 3; k++) acc += V[u][k] * rs[k] * V[v][k];
      st[3 + u * 3 + v] = acc;
    }
}

// ---------------------------------------------------------------------------
// K6: FFN1, whitening fused on read, W chunks in LDS.
// grid (32 ntiles-8, 8 co-tiles-32, B) = 512 blocks. Thread: (co, n).
// ---------------------------------------------------------------------------
__global__ __launch_bounds__(256) void k_ffn1(
    const float* __restrict__ y1, const float* __restrict__ stats,
    const float* __restrict__ gamma, const float* __restrict__ Wfeat,
    const float* __restrict__ Wdir, float* __restrict__ hout)
{
  const int nt = blockIdx.x, cs = blockIdx.y, b = blockIdx.z;
  const int n0 = nt * 8, co0 = cs * 32;
  const int t = threadIdx.x;
  __shared__ float xt[CC][24];     // [ci][v*8+nn] whitened, 12 KB
  __shared__ float Wfl[32][33], Wdl[32][33];
  const float* yb = y1 + (size_t)b * CC * COLS;
  const float* st = stats + b * 12;
  for (int idx = t; idx < CC * 8; idx += 256) {
    int ci = idx >> 3, nn = idx & 7;
    const float* row = yb + ci * COLS + n0 + nn;
    float d0 = row[0] - st[0], d1 = row[256] - st[1], d2 = row[512] - st[2];
    float g = gamma[ci];
    xt[ci][nn]      = g * (st[3] * d0 + st[4] * d1 + st[5] * d2);
    xt[ci][8 + nn]  = g * (st[6] * d0 + st[7] * d1 + st[8] * d2);
    xt[ci][16 + nn] = g * (st[9] * d0 + st[10] * d1 + st[11] * d2);
  }
  const int co = t >> 3, nn = t & 7;
  float p[3] = {0.f, 0.f, 0.f}, d[3] = {0.f, 0.f, 0.f};
  for (int cu = 0; cu < 4; cu++) {
    __syncthreads();
    for (int idx = t; idx < 2048; idx += 256) {
      int row = (idx & 1023) >> 5, ci = idx & 31;
      if (idx < 1024) Wfl[row][ci] = Wfeat[(size_t)(co0 + row) * CC + cu * 32 + ci];
      else            Wdl[row][ci] = Wdir[(size_t)(co0 + row) * CC + cu * 32 + ci];
    }
    __syncthreads();
#pragma unroll 8
    for (int ci = 0; ci < 32; ci++) {
      float wf = Wfl[co][ci], wd = Wdl[co][ci];
      const float* xr = xt[cu * 32 + ci];
      float x0 = xr[nn], x1 = xr[8 + nn], x2 = xr[16 + nn];
      p[0] = fmaf(wf, x0, p[0]); p[1] = fmaf(wf, x1, p[1]); p[2] = fmaf(wf, x2, p[2]);
      d[0] = fmaf(wd, x0, d[0]); d[1] = fmaf(wd, x1, d[1]); d[2] = fmaf(wd, x2, d[2]);
    }
  }
  float dot = p[0] * d[0] + p[1] * d[1] + p[2] * d[2];
  float dsq = d[0] * d[0] + d[1] * d[1] + d[2] * d[2];
  float coef = (dot >= 0.f) ? 0.f : (1.f - NEG_FFN) * dot / (dsq + 1e-6f);
  float* hb = hout + (size_t)(b * CHX + co0 + co) * COLS;
#pragma unroll
  for (int v = 0; v < 3; v++)
    hb[v * 256 + n0 + nn] = p[v] - coef * d[v];
}

// ---------------------------------------------------------------------------
// K7: x2 = whiten(y1) + Wffn2 @ h. grid (48 coltiles-16, 2 cohalf, B).
// ---------------------------------------------------------------------------
__global__ __launch_bounds__(256) void k_ffn2(
    const float* __restrict__ h, const float* __restrict__ Wffn2,
    const float* __restrict__ y1, const float* __restrict__ stats,
    const float* __restrict__ gamma, float* __restrict__ x2)
{
  const int ct = blockIdx.x, cohalf = blockIdx.y, b = blockIdx.z;
  const int col0 = ct * 16, co0 = cohalf * 64;
  const int t = threadIdx.x;
  __shared__ __align__(16) float ht[CHX][16];  // 16 KB
  __shared__ float Wl[64][33];
  const float* hb = h + (size_t)b * CHX * COLS;
  for (int idx = t; idx < CHX * 16; idx += 256) {
    int r = idx >> 4, cc = idx & 15;
    ht[r][cc] = hb[r * COLS + col0 + cc];
  }
  const int cop = t >> 3, colp = t & 7;
  float acc[2][2] = {{0.f, 0.f}, {0.f, 0.f}};
  for (int cu = 0; cu < 8; cu++) {
    __syncthreads();
    for (int idx = t; idx < 64 * 32; idx += 256) {
      int row = idx >> 5, ci = idx & 31;
      Wl[row][ci] = Wffn2[(size_t)(co0 + row) * CHX + cu * 32 + ci];
    }
    __syncthreads();
#pragma unroll 8
    for (int ci = 0; ci < 32; ci++) {
      float w0 = Wl[cop * 2][ci], w1 = Wl[cop * 2 + 1][ci];
      const float2 xv = *(reinterpret_cast<const float2*>(ht[cu * 32 + ci]) + colp);
      acc[0][0] = fmaf(w0, xv.x, acc[0][0]); acc[0][1] = fmaf(w0, xv.y, acc[0][1]);
      acc[1][0] = fmaf(w1, xv.x, acc[1][0]); acc[1][1] = fmaf(w1, xv.y, acc[1][1]);
    }
  }
  const int col_base = col0 + colp * 2;
  const int v = col_base >> 8, n = col_base & 255;
  const float* st = stats + b * 12;
  const float w0 = st[3 + v * 3 + 0], w1 = st[3 + v * 3 + 1], w2 = st[3 + v * 3 + 2];
#pragma unroll
  for (int r = 0; r < 2; r++) {
    const int co_g = co0 + cop * 2 + r;
    const float g = gamma[co_g];
    const float* yr = y1 + (size_t)(b * CC + co_g) * COLS + n;
    const size_t base = (size_t)(b * CC + co_g) * COLS + col_base;
#pragma unroll
    for (int k = 0; k < 2; k++) {
      float d0 = yr[k] - st[0], d1 = yr[256 + k] - st[1], d2 = yr[512 + k] - st[2];
      x2[base + k] = g * (w0 * d0 + w1 * d1 + w2 * d2) + acc[r][k];
    }
  }
}

// ---------------------------------------------------------------------------
// K8: final whitening apply -> out. grid (256), 256 thr.
// ---------------------------------------------------------------------------
__global__ __launch_bounds__(256) void k_zca_apply(
    const float* __restrict__ y, const float* __restrict__ stats,
    const float* __restrict__ gamma, float* __restrict__ out)
{
  int idx = blockIdx.x * blockDim.x + threadIdx.x;
  int b = idx >> 15, rem = idx & 32767;
  int cidx = rem >> 8, n = rem & 255;
  const float* st = stats + b * 12;
  const size_t base = (size_t)(b * CC + cidx) * COLS + n;
  float v0 = y[base] - st[0];
  float v1 = y[base + 256] - st[1];
  float v2 = y[base + 512] - st[2];
  float g = gamma[cidx];
  out[base]       = g * (st[3] * v0 + st[4] * v1 + st[5] * v2);
  out[base + 256] = g * (st[6] * v0 + st[7] * v1 + st[8] * v2);
  out[base + 512] = g * (st[9] * v0 + st[10] * v1 + st[11] * v2);
}

// ---------------------------------------------------------------------------
extern "C" void kernel_launch(void* const* d_in, const int* in_sizes, int n_in,
                              void* d_out, int out_size, void* d_ws, size_t ws_size,
                              hipStream_t stream)
{
  (void)in_sizes; (void)n_in; (void)out_size; (void)ws_size;
  const float* x      = (const float*)d_in[0];
  const float* pos    = (const float*)d_in[1];
  const float* Wq     = (const float*)d_in[2];
  const float* Wk     = (const float*)d_in[3];
  const float* Wv     = (const float*)d_in[4];
  const float* Wo     = (const float*)d_in[5];
  const float* W1     = (const float*)d_in[6];
  const float* b1     = (const float*)d_in[7];
  const float* W2     = (const float*)d_in[8];
  // d_in[9] = b2 : dropped (softmax shift-invariant per channel)
  const float* gamma1 = (const float*)d_in[10];
  const float* Wfeat  = (const float*)d_in[11];
  const float* Wdir   = (const float*)d_in[12];
  const float* Wffn2  = (const float*)d_in[13];
  const float* gamma2 = (const float*)d_in[14];

  float* ws = (float*)d_ws;
  const size_t SZ = (size_t)BB * CC * 3 * NN;   // 393216 floats
  const size_t RMSZ = (size_t)BB * NN * NN;     // 131072 floats
  float* q_t    = ws;                  // dead after k_rel
  float* k_nat  = ws + SZ;             // dead after k_rel
  float* v_t    = ws + 2 * SZ;         // dead after k_attn
  float* rm_all = ws + 3 * SZ;         // dead after k_attn
  float* rp_all = ws + 3 * SZ + RMSZ;  // dead after k_attn
  float* a_nat  = ws;                  // alias q_t
  float* y1     = ws + SZ;             // alias k_nat
  float* hbuf   = ws + 2 * SZ;         // [2SZ, 4SZ), alias v_t+rm+rp
  float* x2     = ws;                  // alias a_nat (dead after k_wo_res)
  float* part   = ws + 4 * SZ;         // 576 floats
  float* stats1 = ws + 4 * SZ + 640;   // 24 floats
  float* stats2 = ws + 4 * SZ + 704;   // 24 floats

  k_qkv<<<dim3(24, 6, BB), 256, 0, stream>>>(x, Wq, Wk, Wv, q_t, k_nat, v_t);
  k_rel<<<dim3(NN / 2, BB), 256, 0, stream>>>(q_t, k_nat, pos, rm_all, rp_all);
  k_attn<<<dim3(NN, 2, BB), 256, 0, stream>>>(rm_all, rp_all, v_t, W1, b1, W2, a_nat);
  k_wo_res<<<dim3(48, 2, BB), 256, 0, stream>>>(a_nat, Wo, x, y1);
  k_stats1<<<dim3(32, BB), 256, 0, stream>>>(y1, part);
  k_zca_fin<<<BB, 64, 0, stream>>>(part, stats1);
  k_ffn1<<<dim3(32, 8, BB), 256, 0, stream>>>(y1, stats1, gamma1, Wfeat, Wdir, hbuf);
  k_ffn2<<<dim3(48, 2, BB), 256, 0, stream>>>(hbuf, Wffn2, y1, stats1, gamma1, x2);
  k_stats1<<<dim3(32, BB), 256, 0, stream>>>(x2, part);
  k_zca_fin<<<BB, 64, 0, stream>>>(part, stats2);
  k_zca_apply<<<256, 256, 0, stream>>>(x2, stats2, gamma2, (float*)d_out);
}

// Round 7
// 104.304 us; speedup vs baseline: 1.2358x; 1.1979x over previous
//
#include <hip/hip_runtime.h>
#include <math.h>

// Problem constants (B=2, C=128, N=256, H=64, CH=256)
#define BB 2
#define CC 128
#define NN 256
#define HH 64
#define CHX 256
#define COLS 768           // 3*N flattened (v,n) columns
#define NEG_ATTN 0.2f
#define NEG_FFN 0.1f

typedef __attribute__((ext_vector_type(8))) short short8b;   // 8 bf16 (4 VGPRs)
typedef __attribute__((ext_vector_type(4))) float f32x4;

__device__ __forceinline__ unsigned bf16rne(float x) {
  unsigned u = __float_as_uint(x);
  return (u + 0x7fffu + ((u >> 16) & 1u)) >> 16;
}

// ---------------------------------------------------------------------------
// K1: q,k,v = Wq/Wk/Wv @ x in three layouts (r3 row-gather structure).
//   q_t[b][n][c][3], k_nat[b][c][3][n], v_t3[b][n][c][3]
// grid (48 col-tiles of 16, 3 which, B), 256 threads
// ---------------------------------------------------------------------------
__global__ __launch_bounds__(256) void k_qkv(
    const float* __restrict__ x, const float* __restrict__ Wq,
    const float* __restrict__ Wk, const float* __restrict__ Wv,
    float* __restrict__ q_t, float* __restrict__ k_nat, float* __restrict__ v_t3)
{
  const int ct = blockIdx.x, which = blockIdx.y, b = blockIdx.z;
  const int col0 = ct * 16;
  __shared__ float xt[CC][16];
  const float* xb = x + (size_t)b * CC * COLS;
  for (int idx = threadIdx.x; idx < CC * 16; idx += 256) {
    int r = idx >> 4, cc = idx & 15;
    xt[r][cc] = xb[r * COLS + col0 + cc];
  }
  __syncthreads();
  const float* W = (which == 0) ? Wq : ((which == 1) ? Wk : Wv);
  const int co = threadIdx.x >> 1;
  const int cc0 = (threadIdx.x & 1) * 8;
  float acc[8];
#pragma unroll
  for (int k = 0; k < 8; k++) acc[k] = 0.f;
  const float* wrow = W + co * CC;
  for (int ci = 0; ci < CC; ci++) {
    float wv = wrow[ci];
#pragma unroll
    for (int k = 0; k < 8; k++) acc[k] = fmaf(wv, xt[ci][cc0 + k], acc[k]);
  }
#pragma unroll
  for (int k = 0; k < 8; k++) {
    int col = col0 + cc0 + k;
    int v = col >> 8, n = col & 255;
    float val = acc[k];
    if (which == 0)      q_t[((size_t)(b * NN + n) * CC + co) * 3 + v] = val;
    else if (which == 1) k_nat[(size_t)(b * CC + co) * COLS + col] = val;
    else                 v_t3[((size_t)(b * NN + n) * CC + co) * 3 + v] = val;
  }
}

// ---------------------------------------------------------------------------
// K1b: rel norms: rm_all[b][i][j], rp_all[b][i][j]. grid (N, B), thread = j.
// (r4 unpaired version: 512 blocks for occupancy)
// ---------------------------------------------------------------------------
__global__ __launch_bounds__(256) void k_rel(
    const float* __restrict__ q_t, const float* __restrict__ k_nat,
    const float* __restrict__ pos, float* __restrict__ rm_all,
    float* __restrict__ rp_all)
{
  const int i = blockIdx.x, b = blockIdx.y;
  const int t = threadIdx.x;
  __shared__ float qv[CC * 3];
  for (int idx = t; idx < CC * 3; idx += 256)
    qv[idx] = q_t[(size_t)(b * NN + i) * CC * 3 + idx];
  __syncthreads();
  const int j = t;
  const float* kb = k_nat + (size_t)b * CC * COLS;
  float p0 = 0.f, p1 = 0.f, p2 = 0.f, p3 = 0.f;
  for (int c = 0; c < CC; c += 4) {
    float kx0 = kb[(c + 0) * COLS + j], ky0 = kb[(c + 0) * COLS + 256 + j], kz0 = kb[(c + 0) * COLS + 512 + j];
    float kx1 = kb[(c + 1) * COLS + j], ky1 = kb[(c + 1) * COLS + 256 + j], kz1 = kb[(c + 1) * COLS + 512 + j];
    float kx2 = kb[(c + 2) * COLS + j], ky2 = kb[(c + 2) * COLS + 256 + j], kz2 = kb[(c + 2) * COLS + 512 + j];
    float kx3 = kb[(c + 3) * COLS + j], ky3 = kb[(c + 3) * COLS + 256 + j], kz3 = kb[(c + 3) * COLS + 512 + j];
    float dx, dy, dz, sq;
    dx = kx0 - qv[(c + 0) * 3]; dy = ky0 - qv[(c + 0) * 3 + 1]; dz = kz0 - qv[(c + 0) * 3 + 2];
    sq = dx * dx + dy * dy + dz * dz; p0 += (sq > 0.f) ? sqrtf(sq) : 0.f;
    dx = kx1 - qv[(c + 1) * 3]; dy = ky1 - qv[(c + 1) * 3 + 1]; dz = kz1 - qv[(c + 1) * 3 + 2];
    sq = dx * dx + dy * dy + dz * dz; p1 += (sq > 0.f) ? sqrtf(sq) : 0.f;
    dx = kx2 - qv[(c + 2) * 3]; dy = ky2 - qv[(c + 2) * 3 + 1]; dz = kz2 - qv[(c + 2) * 3 + 2];
    sq = dx * dx + dy * dy + dz * dz; p2 += (sq > 0.f) ? sqrtf(sq) : 0.f;
    dx = kx3 - qv[(c + 3) * 3]; dy = ky3 - qv[(c + 3) * 3 + 1]; dz = kz3 - qv[(c + 3) * 3 + 2];
    sq = dx * dx + dy * dy + dz * dz; p3 += (sq > 0.f) ? sqrtf(sq) : 0.f;
  }
  rm_all[(size_t)(b * NN + i) * NN + j] = ((p0 + p1) + (p2 + p3)) * (1.f / 128.f);
  float dx = pos[(b * NN + i) * 3 + 0] - pos[(b * NN + j) * 3 + 0];
  float dy = pos[(b * NN + i) * 3 + 1] - pos[(b * NN + j) * 3 + 1];
  float dz = pos[(b * NN + i) * 3 + 2] - pos[(b * NN + j) * 3 + 2];
  float sq = dx * dx + dy * dy + dz * dz;
  rp_all[(size_t)(b * NN + i) * NN + j] = (sq > 0.f) ? sqrtf(sq) : 0.f;
}

// ---------------------------------------------------------------------------
// K2: fused attention per (b, i, c-half). grid (N, 2, B), 256 threads.
// MFMA -> fp32 scores to padded LDS -> coalesced PV (c = lane, V as [n][c][3]
// so each lane reads 12 contiguous bytes). No running max (scores bounded).
// ---------------------------------------------------------------------------
__global__ __launch_bounds__(256, 4) void k_attn(
    const float* __restrict__ rm_all, const float* __restrict__ rp_all,
    const float* __restrict__ v_t3, const float* __restrict__ W1,
    const float* __restrict__ b1, const float* __restrict__ W2,
    float* __restrict__ a_nat)
{
  const int i = blockIdx.x, chalf = blockIdx.y, b = blockIdx.z;
  const int t = threadIdx.x;
  __shared__ __align__(16) short hh_s[64 * 64];   // bf16 bits, XOR-swizzled
  __shared__ __align__(16) short w2_s[64 * 64];   // bf16 bits, XOR-swizzled
  __shared__ float sc_s[64 * 65];                 // fp32 scores (padded)
  __shared__ float rm_s[NN], rp_s[NN];

  rm_s[t] = rm_all[(size_t)(b * NN + i) * NN + t];
  rp_s[t] = rp_all[(size_t)(b * NN + i) * NN + t];
  {
    const int cl = t >> 2, h0 = (t & 3) * 16;
    const float* wrow = W2 + (size_t)(chalf * 64 + cl) * HH + h0;
#pragma unroll
    for (int e = 0; e < 8; e++) {
      unsigned lo = bf16rne(wrow[2 * e]);
      unsigned hi = bf16rne(wrow[2 * e + 1]);
      int didx = (cl * 32 + (h0 >> 1) + e) ^ ((cl & 7) << 2);
      ((unsigned*)w2_s)[didx] = lo | (hi << 16);
    }
  }
  const int h2 = (t & 31) * 2, jgrp = t >> 5;
  const float4 w1v = *reinterpret_cast<const float4*>(W1 + 2 * h2);
  const float c0 = b1[h2], c1 = b1[h2 + 1];
  __syncthreads();

  auto phase2 = [&](int q) {
#pragma unroll
    for (int jj = 0; jj < 8; jj++) {
      int jl = jgrp * 8 + jj;
      int jg = q * 64 + jl;
      float rmv = rm_s[jg], rpv = rp_s[jg];
      float g0 = fmaf(w1v.x, rmv, fmaf(w1v.y, rpv, c0));
      float g1 = fmaf(w1v.z, rmv, fmaf(w1v.w, rpv, c1));
      g0 = (g0 >= 0.f) ? g0 : NEG_ATTN * g0;
      g1 = (g1 >= 0.f) ? g1 : NEG_ATTN * g1;
      int didx = (jl * 32 + (h2 >> 1)) ^ ((jl & 7) << 2);
      ((unsigned*)hh_s)[didx] = bf16rne(g0) | (bf16rne(g1) << 16);
    }
  };

  phase2(0);
  __syncthreads();

  const int lane = t & 63, wv = t >> 6;
  const int g8 = (lane >> 4) * 8;
  const int cdx = wv * 16 + (lane & 15);
  const short8b bfr0 = *reinterpret_cast<const short8b*>(&w2_s[(cdx * 64 + g8) ^ ((cdx & 7) << 3)]);
  const short8b bfr1 = *reinterpret_cast<const short8b*>(&w2_s[(cdx * 64 + 32 + g8) ^ ((cdx & 7) << 3)]);

  const int cl = lane;
  const int par = wv;
  const int vc = chalf * 64 + cl;
  float l = 0.f, a0 = 0.f, a1 = 0.f, a2 = 0.f;

  for (int q = 0; q < 4; q++) {
#pragma unroll
    for (int jt = 0; jt < 4; jt++) {
      int jr = jt * 16 + (lane & 15);
      short8b af0 = *reinterpret_cast<const short8b*>(&hh_s[(jr * 64 + g8) ^ ((jr & 7) << 3)]);
      short8b af1 = *reinterpret_cast<const short8b*>(&hh_s[(jr * 64 + 32 + g8) ^ ((jr & 7) << 3)]);
      f32x4 acc = {0.f, 0.f, 0.f, 0.f};
      acc = __builtin_amdgcn_mfma_f32_16x16x32_bf16(af0, bfr0, acc, 0, 0, 0);
      acc = __builtin_amdgcn_mfma_f32_16x16x32_bf16(af1, bfr1, acc, 0, 0, 0);
      int row0 = jt * 16 + (lane >> 4) * 4;
      int ccol = wv * 16 + (lane & 15);
#pragma unroll
      for (int r = 0; r < 4; r++) sc_s[(row0 + r) * 65 + ccol] = acc[r];
    }
    __syncthreads();
    // ---- PV: exp-sums, no max; V [n][c][3] -> 12 contiguous B per lane ----
#pragma unroll 4
    for (int jj = 0; jj < 16; jj++) {
      int jl = jj * 4 + par;
      int jg = q * 64 + jl;
      float s = sc_s[jl * 65 + cl];
      const float* vb = v_t3 + ((size_t)(b * NN + jg) * CC + vc) * 3;
      float v0 = vb[0], v1 = vb[1], v2 = vb[2];
      float p = __expf(s);
      l += p;
      a0 = fmaf(p, v0, a0);
      a1 = fmaf(p, v1, a1);
      a2 = fmaf(p, v2, a2);
    }
    if (q < 3) phase2(q + 1);
    __syncthreads();
  }

  // ---- merge the 4 j-parities per channel (mrg aliases sc_s) ----
  float* mrg = sc_s;
  if (par != 0) {
    float* mp = mrg + (cl * 3 + (par - 1)) * 4;
    mp[0] = l; mp[1] = a0; mp[2] = a1; mp[3] = a2;
  }
  __syncthreads();
  if (par == 0) {
    float L = l, A0 = a0, A1 = a1, A2 = a2;
#pragma unroll
    for (int q = 0; q < 3; q++) {
      const float* mp = mrg + (cl * 3 + q) * 4;
      L += mp[0]; A0 += mp[1]; A1 += mp[2]; A2 += mp[3];
    }
    float inv = 1.f / L;
    float* ap = a_nat + (size_t)(b * CC + vc) * COLS + i;
    ap[0] = A0 * inv; ap[256] = A1 * inv; ap[512] = A2 * inv;
  }
}

// ---------------------------------------------------------------------------
// K3: y1 = x + Wo @ a_nat.  grid (48 col-tiles of 16, 2 co-halves, B), 256 thr.
// (r3 row-gather structure)
// ---------------------------------------------------------------------------
__global__ __launch_bounds__(256) void k_wo_res(
    const float* __restrict__ a_nat, const float* __restrict__ Wo,
    const float* __restrict__ x, float* __restrict__ y1)
{
  const int ct = blockIdx.x, cohalf = blockIdx.y, b = blockIdx.z;
  const int col0 = ct * 16;
  __shared__ float at[CC][16];
  const float* ab = a_nat + (size_t)b * CC * COLS;
  for (int idx = threadIdx.x; idx < CC * 16; idx += 256) {
    int r = idx >> 4, cc = idx & 15;
    at[r][cc] = ab[r * COLS + col0 + cc];
  }
  __syncthreads();
  const int co = cohalf * 64 + (threadIdx.x >> 2);
  const int cc0 = (threadIdx.x & 3) * 4;
  float acc[4];
#pragma unroll
  for (int k = 0; k < 4; k++) acc[k] = 0.f;
  const float* wrow = Wo + co * CC;
  for (int ci = 0; ci < CC; ci++) {
    float wv = wrow[ci];
#pragma unroll
    for (int k = 0; k < 4; k++) acc[k] = fmaf(wv, at[ci][cc0 + k], acc[k]);
  }
  const size_t base = (size_t)(b * CC + co) * COLS + col0 + cc0;
#pragma unroll
  for (int k = 0; k < 4; k++) y1[base + k] = x[base + k] + acc[k];
}

// ---------------------------------------------------------------------------
// K4: fused ZCA stats + 3x3 Jacobi + whitening matrix. grid (B), 1024 thr.
// (r4 fused version: saves 2 launches)
// ---------------------------------------------------------------------------
__global__ __launch_bounds__(1024) void k_stats(
    const float* __restrict__ y, float* __restrict__ stats)
{
  const int b = blockIdx.x;
  const float* yb = y + (size_t)b * CC * COLS;
  const int t = threadIdx.x;
  float v9[9];
#pragma unroll
  for (int k = 0; k < 9; k++) v9[k] = 0.f;
  for (int e = 0; e < 32; e++) {
    int idx = e * 1024 + t;
    int cidx = idx >> 8, n = idx & 255;
    const float* row = yb + cidx * COLS + n;
    float v0 = row[0], v1 = row[256], v2 = row[512];
    v9[0] += v0; v9[1] += v1; v9[2] += v2;
    v9[3] += v0 * v0; v9[4] += v0 * v1; v9[5] += v0 * v2;
    v9[6] += v1 * v1; v9[7] += v1 * v2; v9[8] += v2 * v2;
  }
#pragma unroll
  for (int off = 32; off >= 1; off >>= 1)
#pragma unroll
    for (int k = 0; k < 9; k++) v9[k] += __shfl_down(v9[k], off);
  __shared__ float red[16][9];
  const int wid = t >> 6, lane = t & 63;
  if (lane == 0)
#pragma unroll
    for (int k = 0; k < 9; k++) red[wid][k] = v9[k];
  __syncthreads();
  if (t == 0) {
    float tot[9];
#pragma unroll
    for (int k = 0; k < 9; k++) tot[k] = 0.f;
    for (int w = 0; w < 16; w++)
#pragma unroll
      for (int k = 0; k < 9; k++) tot[k] += red[w][k];
    const float M = (float)(CC * NN);
    float mu0 = tot[0] / M, mu1 = tot[1] / M, mu2 = tot[2] / M;
    float A[3][3];
    A[0][0] = (tot[3] - M * mu0 * mu0) / M + 1e-5f;
    A[0][1] = A[1][0] = (tot[4] - M * mu0 * mu1) / M;
    A[0][2] = A[2][0] = (tot[5] - M * mu0 * mu2) / M;
    A[1][1] = (tot[6] - M * mu1 * mu1) / M + 1e-5f;
    A[1][2] = A[2][1] = (tot[7] - M * mu1 * mu2) / M;
    A[2][2] = (tot[8] - M * mu2 * mu2) / M + 1e-5f;
    float V[3][3] = {{1.f, 0.f, 0.f}, {0.f, 1.f, 0.f}, {0.f, 0.f, 1.f}};
    for (int sweep = 0; sweep < 10; sweep++) {
      for (int pi = 0; pi < 3; pi++) {
        const int p = (pi == 2) ? 1 : 0;
        const int q = (pi == 0) ? 1 : 2;
        float apq = A[p][q];
        if (fabsf(apq) < 1e-30f) continue;
        float theta = (A[q][q] - A[p][p]) / (2.f * apq);
        float tt = 1.f / (fabsf(theta) + sqrtf(theta * theta + 1.f));
        if (theta < 0.f) tt = -tt;
        float cr = 1.f / sqrtf(tt * tt + 1.f);
        float sr = tt * cr;
        float app = A[p][p], aqq = A[q][q];
        A[p][p] = app - tt * apq;
        A[q][q] = aqq + tt * apq;
        A[p][q] = A[q][p] = 0.f;
        const int r = 3 - p - q;
        float arp = A[r][p], arq = A[r][q];
        A[r][p] = A[p][r] = cr * arp - sr * arq;
        A[r][q] = A[q][r] = sr * arp + cr * arq;
        for (int rr = 0; rr < 3; rr++) {
          float vrp = V[rr][p], vrq = V[rr][q];
          V[rr][p] = cr * vrp - sr * vrq;
          V[rr][q] = sr * vrp + cr * vrq;
        }
      }
    }
    float rs[3];
#pragma unroll
    for (int k = 0; k < 3; k++) rs[k] = rsqrtf(fmaxf(A[k][k], 1e-5f));
    float* st = stats + b * 12;
    st[0] = mu0; st[1] = mu1; st[2] = mu2;
    for (int u = 0; u < 3; u++)
      for (int v = 0; v < 3; v++) {
        float acc = 0.f;
        for (int k = 0; k < 3; k++) acc += V[u][k] * rs[k] * V[v][k];
        st[3 + u * 3 + v] = acc;
      }
  }
}

// ---------------------------------------------------------------------------
// K6: FFN1 with fused whitening on read (r3 row-gather structure).
// grid (16 n-tiles of 16, 4 co-splits of 64, B), 256 thr.
// ---------------------------------------------------------------------------
__global__ __launch_bounds__(256) void k_ffn1(
    const float* __restrict__ y1, const float* __restrict__ stats,
    const float* __restrict__ gamma, const float* __restrict__ Wfeat,
    const float* __restrict__ Wdir, float* __restrict__ hout)
{
  const int nt = blockIdx.x, cs = blockIdx.y, b = blockIdx.z;
  const int n0 = nt * 16, co0 = cs * 64;
  __shared__ float xt[CC][48];  // [ci][v*16+nn], whitened
  const float* yb = y1 + (size_t)b * CC * COLS;
  const float* st = stats + b * 12;
  for (int idx = threadIdx.x; idx < CC * 16; idx += 256) {
    int ci = idx >> 4, nn = idx & 15;
    const float* row = yb + ci * COLS + n0 + nn;
    float d0 = row[0] - st[0], d1 = row[256] - st[1], d2 = row[512] - st[2];
    float g = gamma[ci];
    xt[ci][nn]      = g * (st[3] * d0 + st[4] * d1 + st[5] * d2);
    xt[ci][16 + nn] = g * (st[6] * d0 + st[7] * d1 + st[8] * d2);
    xt[ci][32 + nn] = g * (st[9] * d0 + st[10] * d1 + st[11] * d2);
  }
  __syncthreads();
  const int co = co0 + (threadIdx.x & 63);
  const int nn0 = (threadIdx.x >> 6) * 4;
  float p[3][4], d[3][4];
#pragma unroll
  for (int v = 0; v < 3; v++)
#pragma unroll
    for (int k = 0; k < 4; k++) { p[v][k] = 0.f; d[v][k] = 0.f; }
  const float* wf = Wfeat + co * CC;
  const float* wd = Wdir + co * CC;
  for (int ci = 0; ci < CC; ci++) {
    float a = wf[ci], bb = wd[ci];
#pragma unroll
    for (int v = 0; v < 3; v++)
#pragma unroll
      for (int k = 0; k < 4; k++) {
        float xv = xt[ci][v * 16 + nn0 + k];
        p[v][k] = fmaf(a, xv, p[v][k]);
        d[v][k] = fmaf(bb, xv, d[v][k]);
      }
  }
  float* hb = hout + (size_t)(b * CHX + co) * COLS;
#pragma unroll
  for (int k = 0; k < 4; k++) {
    float dot = p[0][k] * d[0][k] + p[1][k] * d[1][k] + p[2][k] * d[2][k];
    float dsq = d[0][k] * d[0][k] + d[1][k] * d[1][k] + d[2][k] * d[2][k];
    float coef = (dot >= 0.f) ? 0.f : (1.f - NEG_FFN) * dot / (dsq + 1e-6f);
#pragma unroll
    for (int v = 0; v < 3; v++)
      hb[v * 256 + n0 + nn0 + k] = p[v][k] - coef * d[v][k];
  }
}

// ---------------------------------------------------------------------------
// K7: x2 = whiten(y1) + Wffn2 @ h.  grid (48 col-tiles of 16, 2 co-halves, B).
// (r3 row-gather structure)
// ---------------------------------------------------------------------------
__global__ __launch_bounds__(256) void k_ffn2(
    const float* __restrict__ h, const float* __restrict__ Wffn2,
    const float* __restrict__ y1, const float* __restrict__ stats,
    const float* __restrict__ gamma, float* __restrict__ x2)
{
  const int ct = blockIdx.x, cohalf = blockIdx.y, b = blockIdx.z;
  const int col0 = ct * 16;
  __shared__ float ht[CHX][16];
  const float* hb = h + (size_t)b * CHX * COLS;
  for (int idx = threadIdx.x; idx < CHX * 16; idx += 256) {
    int r = idx >> 4, cc = idx & 15;
    ht[r][cc] = hb[r * COLS + col0 + cc];
  }
  __syncthreads();
  const int co = cohalf * 64 + (threadIdx.x >> 2);
  const int cc0 = (threadIdx.x & 3) * 4;
  float acc[4];
#pragma unroll
  for (int k = 0; k < 4; k++) acc[k] = 0.f;
  const float* w = Wffn2 + co * CHX;
  for (int ci = 0; ci < CHX; ci++) {
    float wv = w[ci];
#pragma unroll
    for (int k = 0; k < 4; k++) acc[k] = fmaf(wv, ht[ci][cc0 + k], acc[k]);
  }
  const int col_base = col0 + cc0;
  const int v = col_base >> 8, n = col_base & 255;
  const float* st = stats + b * 12;
  const float* yb = y1 + (size_t)(b * CC + co) * COLS + n;
  const float g = gamma[co];
  const float w0 = st[3 + v * 3 + 0], w1 = st[3 + v * 3 + 1], w2 = st[3 + v * 3 + 2];
  const size_t base = (size_t)(b * CC + co) * COLS + col_base;
#pragma unroll
  for (int k = 0; k < 4; k++) {
    float d0 = yb[k] - st[0], d1 = yb[256 + k] - st[1], d2 = yb[512 + k] - st[2];
    float xw = g * (w0 * d0 + w1 * d1 + w2 * d2);
    x2[base + k] = xw + acc[k];
  }
}

// ---------------------------------------------------------------------------
// K8: final whitening apply -> out. grid (256), 256 thr.
// ---------------------------------------------------------------------------
__global__ __launch_bounds__(256) void k_zca_apply(
    const float* __restrict__ y, const float* __restrict__ stats,
    const float* __restrict__ gamma, float* __restrict__ out)
{
  int idx = blockIdx.x * blockDim.x + threadIdx.x;
  int b = idx >> 15, rem = idx & 32767;
  int cidx = rem >> 8, n = rem & 255;
  const float* st = stats + b * 12;
  const size_t base = (size_t)(b * CC + cidx) * COLS + n;
  float v0 = y[base] - st[0];
  float v1 = y[base + 256] - st[1];
  float v2 = y[base + 512] - st[2];
  float g = gamma[cidx];
  out[base]       = g * (st[3] * v0 + st[4] * v1 + st[5] * v2);
  out[base + 256] = g * (st[6] * v0 + st[7] * v1 + st[8] * v2);
  out[base + 512] = g * (st[9] * v0 + st[10] * v1 + st[11] * v2);
}

// ---------------------------------------------------------------------------
extern "C" void kernel_launch(void* const* d_in, const int* in_sizes, int n_in,
                              void* d_out, int out_size, void* d_ws, size_t ws_size,
                              hipStream_t stream)
{
  (void)in_sizes; (void)n_in; (void)out_size; (void)ws_size;
  const float* x      = (const float*)d_in[0];
  const float* pos    = (const float*)d_in[1];
  const float* Wq     = (const float*)d_in[2];
  const float* Wk     = (const float*)d_in[3];
  const float* Wv     = (const float*)d_in[4];
  const float* Wo     = (const float*)d_in[5];
  const float* W1     = (const float*)d_in[6];
  const float* b1     = (const float*)d_in[7];
  const float* W2     = (const float*)d_in[8];
  // d_in[9] = b2 : dropped (softmax shift-invariant per channel)
  const float* gamma1 = (const float*)d_in[10];
  const float* Wfeat  = (const float*)d_in[11];
  const float* Wdir   = (const float*)d_in[12];
  const float* Wffn2  = (const float*)d_in[13];
  const float* gamma2 = (const float*)d_in[14];

  float* ws = (float*)d_ws;
  const size_t SZ = (size_t)BB * CC * 3 * NN;   // 393216 floats
  const size_t RMSZ = (size_t)BB * NN * NN;     // 131072 floats
  float* q_t    = ws;                  // dead after k_rel
  float* k_nat  = ws + SZ;             // dead after k_rel
  float* v_t3   = ws + 2 * SZ;         // dead after k_attn
  float* rm_all = ws + 3 * SZ;         // dead after k_attn
  float* rp_all = ws + 3 * SZ + RMSZ;  // dead after k_attn
  float* a_nat  = ws;                  // alias q_t
  float* y1     = ws + SZ;             // alias k_nat
  float* hbuf   = ws + 2 * SZ;         // [2SZ, 4SZ), alias v_t3+rm+rp
  float* x2     = ws;                  // alias a_nat (dead after k_wo_res)
  float* stats1 = ws + 4 * SZ;         // 24 floats
  float* stats2 = ws + 4 * SZ + 64;    // 24 floats

  k_qkv<<<dim3(48, 3, BB), 256, 0, stream>>>(x, Wq, Wk, Wv, q_t, k_nat, v_t3);
  k_rel<<<dim3(NN, BB), 256, 0, stream>>>(q_t, k_nat, pos, rm_all, rp_all);
  k_attn<<<dim3(NN, 2, BB), 256, 0, stream>>>(rm_all, rp_all, v_t3, W1, b1, W2, a_nat);
  k_wo_res<<<dim3(48, 2, BB), 256, 0, stream>>>(a_nat, Wo, x, y1);
  k_stats<<<BB, 1024, 0, stream>>>(y1, stats1);
  k_ffn1<<<dim3(16, 4, BB), 256, 0, stream>>>(y1, stats1, gamma1, Wfeat, Wdir, hbuf);
  k_ffn2<<<dim3(48, 2, BB), 256, 0, stream>>>(hbuf, Wffn2, y1, stats1, gamma1, x2);
  k_stats<<<BB, 1024, 0, stream>>>(x2, stats2);
  k_zca_apply<<<256, 256, 0, stream>>>(x2, stats2, gamma2, (float*)d_out);
}